// Round 15
// baseline (284.070 us; speedup 1.0000x reference)
//
#include <hip/hip_runtime.h>
#include <math.h>

typedef int v4i  __attribute__((ext_vector_type(4)));
typedef int v16i __attribute__((ext_vector_type(16)));

#define DIM 4096
#define BM 256              // output tile (BM x BM)
#define BK 64               // K-tile bytes (int8)
#define ABUF 16384          // one A buffer: 256 rows x 64 B (A only in LDS)

// ---------------------------------------------------------------------------
// async global->LDS 16B copy (wave-uniform base + lane*16 destination rule)
// ---------------------------------------------------------------------------
__device__ __forceinline__ void async16(const void* g, void* l) {
    __builtin_amdgcn_global_load_lds((__attribute__((address_space(1))) void*)(g),
                                     (__attribute__((address_space(3))) void*)(l),
                                     16, 0, 0);
}

// raw barrier / counted waitcnt (T4): no implicit vmcnt(0) drain.
#define VMCNT(N) asm volatile("s_waitcnt vmcnt(" #N ")" ::: "memory")
#define BARRIER() asm volatile("s_barrier" ::: "memory")

// ---------------------------------------------------------------------------
// Fused prep (passed R10/R11/R13/R14): FWHT(256)+quant via rinv multiply;
// weight narrowing int32->int8.
// ---------------------------------------------------------------------------
__global__ __launch_bounds__(256) void prep(const float* __restrict__ x,
                                            const int* __restrict__ w,
                                            signed char* __restrict__ q,
                                            signed char* __restrict__ w8,
                                            float* __restrict__ scales) {
    if (blockIdx.x >= 4096) {
        int i = (blockIdx.x - 4096) * 256 + threadIdx.x;
        int4 v = ((const int4*)w)[i];
        char4 c;
        c.x = (signed char)v.x; c.y = (signed char)v.y;
        c.z = (signed char)v.z; c.w = (signed char)v.w;
        ((char4*)w8)[i] = c;
        return;
    }
    const int row  = blockIdx.x;
    const int lane = threadIdx.x & 63;
    const int wave = threadIdx.x >> 6;
    const float4* xr4 = (const float4*)(x + (size_t)row * DIM);

    float sgn[6];
    #pragma unroll
    for (int i = 0; i < 6; ++i) sgn[i] = (lane & (1 << i)) ? -1.0f : 1.0f;

    float f[4][4];                      // UNSCALED FWHT values (x 16 vs ref)
    #pragma unroll
    for (int b = 0; b < 4; ++b) {
        const int blk = wave + 4 * b;
        float4 v = xr4[blk * 64 + lane];
        float t0 = v.x + v.y, t1 = v.x - v.y;
        float t2 = v.z + v.w, t3 = v.z - v.w;
        f[b][0] = t0 + t2; f[b][1] = t1 + t3;
        f[b][2] = t0 - t2; f[b][3] = t1 - t3;
        #pragma unroll
        for (int st = 0; st < 6; ++st) {
            const int m = 1 << st;
            #pragma unroll
            for (int j = 0; j < 4; ++j) {
                float p = __shfl_xor(f[b][j], m, 64);
                f[b][j] = fmaf(sgn[st], f[b][j], p);
            }
        }
    }

    float m = 0.0f;
    #pragma unroll
    for (int b = 0; b < 4; ++b)
        #pragma unroll
        for (int j = 0; j < 4; ++j) m = fmaxf(m, fabsf(f[b][j]));
    #pragma unroll
    for (int d = 32; d; d >>= 1) m = fmaxf(m, __shfl_xor(m, d, 64));
    __shared__ float sm[4];
    if (lane == 0) sm[wave] = m;
    __syncthreads();
    m = fmaxf(fmaxf(sm[0], sm[1]), fmaxf(sm[2], sm[3]));

    const float s = (m * 0.0625f) / 7.0f;   // identical value to verified ver.
    if (threadIdx.x == 0) scales[row] = s;
    const float rinv = 7.0f / m;            // quant reciprocal (unscaled dom.)

    char4* qr4 = (char4*)(q + (size_t)row * DIM);
    #pragma unroll
    for (int b = 0; b < 4; ++b) {
        const int blk = wave + 4 * b;
        char4 c;
        int qi;
        qi = (int)rintf(f[b][0] * rinv); c.x = (signed char)min(7, max(-8, qi));
        qi = (int)rintf(f[b][1] * rinv); c.y = (signed char)min(7, max(-8, qi));
        qi = (int)rintf(f[b][2] * rinv); c.z = (signed char)min(7, max(-8, qi));
        qi = (int)rintf(f[b][3] * rinv); c.w = (signed char)min(7, max(-8, qi));
        qr4[blk * 64 + lane] = c;
    }
}

// ---------------------------------------------------------------------------
// int8 GEMM, 256x256 tile, BK=64, 8 waves (2M x 4N).
//
// R14 post-mortem: bank conflicts -> 0 changed nothing; LDS PORT VOLUME is
// the structural bottleneck (96 b128 reads + 32KB DMA ~ 1550 cyc/tile >
// 1171 cyc MFMA floor).  This version removes B from LDS entirely:
//  - A: LDS, 3 buffers x 16KB, fragment-order layout (R14-verified, 0
//    conflicts), staged 2 tiles ahead via global_load_lds; inline
//    compiler-scheduled frag reads (R10 style -- no manual reg pipeline).
//  - B: direct global->register, 3 rotating register sets (b0/b1/b2,
//    4 x v4i each), loaded 2 tiles ahead.  WAR target was last consumed a
//    full substep (~2000 cyc) earlier -- fixes R14's mid-substep WAR stall.
//    B-panel is L2-resident (~6-8 TB/s aggregate demand << 34.5 TB/s).
//  - LDS port/tile drops to ~900 cyc (64 reads + 16KB DMA) < MFMA floor.
//  - vmcnt: per substep issues {2 A-DMA, 4 B-loads}; VMCNT(6) at substep
//    top proves tile t's A and B complete (in-flight: t+1's 6 ops).
// ---------------------------------------------------------------------------
__global__ __launch_bounds__(512, 2) void gemm_q8(const signed char* __restrict__ A,
                                                  const signed char* __restrict__ B,
                                                  const float* __restrict__ rowScale,
                                                  const float* __restrict__ wscale,
                                                  const float* __restrict__ bias,
                                                  float* __restrict__ out) {
    __shared__ __align__(16) signed char S[3 * ABUF];   // 48 KB (A only)

    // XCD swizzle: 256 blocks -> each XCD a 4(bm) x 8(bn) rectangle.
    const int flat = blockIdx.y * gridDim.x + blockIdx.x;
    const int xcd  = flat & 7;
    const int idx  = flat >> 3;                 // 0..31
    const int bm   = ((xcd >> 1) << 2) + (idx & 3);
    const int bn   = ((xcd & 1) << 3) + (idx >> 2);

    const int t = threadIdx.x;
    const int lane = t & 63;
    const int wave = t >> 6;                    // 0..7
    const int wm = (wave >> 2) * 128;           // 2 waves in M
    const int wn = (wave & 3) * 64;             // 4 waves in N
    const int l31 = lane & 31, lh = lane >> 5;

    // --- A staging (fragment-order source, linear LDS dest; R14-verified).
    // slot cidx -> block b=cidx>>6 (g=b>>1 rowgroup, sH=b&1 k-half),
    // l=cidx&63 -> row g*32+(l&31), kbytes sH*32+(l>>5)*16.
    const signed char* ga[2];
    int ldsA[2];
    #pragma unroll
    for (int h = 0; h < 2; ++h) {
        const int cidx = t + 512 * h;           // 0..1023
        const int b    = cidx >> 6;             // 0..15
        const int g    = b >> 1;                // rowgroup 0..7
        const int sH   = b & 1;                 // k-half
        const int l    = cidx & 63;
        const int row  = g * 32 + (l & 31);
        const int kb   = sH * 32 + (l >> 5) * 16;
        ga[h] = A + (size_t)(bm * BM + row) * DIM + kb;
        ldsA[h] = cidx * 16;                    // linear LDS dest
    }

    // --- B per-lane global pointers for the 4 (j,s) fragments.
    // byte = (bn*256 + wn + j*32 + l31)*DIM + s*32 + lh*16; advance +64/tile.
    const signed char* pb[4];
    #pragma unroll
    for (int j = 0; j < 2; ++j)
        #pragma unroll
        for (int s = 0; s < 2; ++s)
            pb[j * 2 + s] = B + (size_t)(bn * BM + wn + j * 32 + l31) * DIM
                              + s * 32 + lh * 16;

    // --- A read base (frag-order): block (g,s) at g*2048 + s*1024.
    const signed char* rbA = &S[(wave >> 2) * 8192 + lane * 16];

    v16i acc[4][2] = {};
    v4i b0[4], b1[4], b2[4];            // B register sets (tile%3 rotation)

#define STAGE_A(P3) do {                                                       \
        async16(ga[0], &S[(P3) * ABUF + ldsA[0]]); ga[0] += BK;                \
        async16(ga[1], &S[(P3) * ABUF + ldsA[1]]); ga[1] += BK;                \
    } while (0)

#define B_LOAD(BS) do {                                                        \
        BS[0] = *(const v4i*)pb[0]; pb[0] += BK;                               \
        BS[1] = *(const v4i*)pb[1]; pb[1] += BK;                               \
        BS[2] = *(const v4i*)pb[2]; pb[2] += BK;                               \
        BS[3] = *(const v4i*)pb[3]; pb[3] += BK;                               \
    } while (0)

    // COMPUTE tile in A-buffer P3 with B set BS.  BS[j*2+s].
#define COMPUTE(P3, BS) do {                                                   \
        const signed char* rb = rbA + (P3) * ABUF;                             \
        __builtin_amdgcn_s_setprio(1);                                         \
        {                                                                      \
            const v4i a0 = *(const v4i*)(rb);                                  \
            const v4i a1 = *(const v4i*)(rb + 2048);                           \
            const v4i a2 = *(const v4i*)(rb + 4096);                           \
            const v4i a3 = *(const v4i*)(rb + 6144);                           \
            acc[0][0] = __builtin_amdgcn_mfma_i32_32x32x32_i8(a0, BS[0], acc[0][0], 0, 0, 0); \
            acc[0][1] = __builtin_amdgcn_mfma_i32_32x32x32_i8(a0, BS[2], acc[0][1], 0, 0, 0); \
            acc[1][0] = __builtin_amdgcn_mfma_i32_32x32x32_i8(a1, BS[0], acc[1][0], 0, 0, 0); \
            acc[1][1] = __builtin_amdgcn_mfma_i32_32x32x32_i8(a1, BS[2], acc[1][1], 0, 0, 0); \
            acc[2][0] = __builtin_amdgcn_mfma_i32_32x32x32_i8(a2, BS[0], acc[2][0], 0, 0, 0); \
            acc[2][1] = __builtin_amdgcn_mfma_i32_32x32x32_i8(a2, BS[2], acc[2][1], 0, 0, 0); \
            acc[3][0] = __builtin_amdgcn_mfma_i32_32x32x32_i8(a3, BS[0], acc[3][0], 0, 0, 0); \
            acc[3][1] = __builtin_amdgcn_mfma_i32_32x32x32_i8(a3, BS[2], acc[3][1], 0, 0, 0); \
        }                                                                      \
        {                                                                      \
            const v4i a0 = *(const v4i*)(rb + 1024);                           \
            const v4i a1 = *(const v4i*)(rb + 3072);                           \
            const v4i a2 = *(const v4i*)(rb + 5120);                           \
            const v4i a3 = *(const v4i*)(rb + 7168);                           \
            acc[0][0] = __builtin_amdgcn_mfma_i32_32x32x32_i8(a0, BS[1], acc[0][0], 0, 0, 0); \
            acc[0][1] = __builtin_amdgcn_mfma_i32_32x32x32_i8(a0, BS[3], acc[0][1], 0, 0, 0); \
            acc[1][0] = __builtin_amdgcn_mfma_i32_32x32x32_i8(a1, BS[1], acc[1][0], 0, 0, 0); \
            acc[1][1] = __builtin_amdgcn_mfma_i32_32x32x32_i8(a1, BS[3], acc[1][1], 0, 0, 0); \
            acc[2][0] = __builtin_amdgcn_mfma_i32_32x32x32_i8(a2, BS[1], acc[2][0], 0, 0, 0); \
            acc[2][1] = __builtin_amdgcn_mfma_i32_32x32x32_i8(a2, BS[3], acc[2][1], 0, 0, 0); \
            acc[3][0] = __builtin_amdgcn_mfma_i32_32x32x32_i8(a3, BS[1], acc[3][0], 0, 0, 0); \
            acc[3][1] = __builtin_amdgcn_mfma_i32_32x32x32_i8(a3, BS[3], acc[3][1], 0, 0, 0); \
        }                                                                      \
        __builtin_amdgcn_s_setprio(0);                                         \
    } while (0)

    // substep: wait tile T, stage/load tile T+2 (if any), compute T.
    // In-flight at VMCNT: {A(T+1),B(T+1)} = 6 ops -> VMCNT(6).
#define SUB(P3, FILL3, BSU, BSF, VN) do {                                      \
        VMCNT(VN); BARRIER();                                                  \
        STAGE_A(FILL3);                                                        \
        B_LOAD(BSF);                                                           \
        COMPUTE(P3, BSU);                                                      \
    } while (0)

#define SUB_NS(P3, BSU, VN) do {                                               \
        VMCNT(VN); BARRIER();                                                  \
        COMPUTE(P3, BSU);                                                      \
    } while (0)

    // 64 K-tiles, tile T -> A-buf/B-set T%3, loaded 2 ahead.
    STAGE_A(0); B_LOAD(b0);              // tile 0
    STAGE_A(1); B_LOAD(b1);              // tile 1
    #pragma unroll 1
    for (int it = 0; it < 20; ++it) {    // tiles 3it+0 .. 3it+2
        SUB(0, 2, b0, b2, 6);            // compute 3it+0, fetch 3it+2
        SUB(1, 0, b1, b0, 6);            // compute 3it+1, fetch 3it+3
        SUB(2, 1, b2, b1, 6);            // compute 3it+2, fetch 3it+4
    }
    SUB(0, 2, b0, b2, 6);                // compute 60, fetch 62
    SUB(1, 0, b1, b0, 6);                // compute 61, fetch 63
    SUB_NS(2, b2, 6);                    // compute 62 (63's 6 ops in flight)
    SUB_NS(0, b0, 0);                    // compute 63

#undef SUB
#undef SUB_NS
#undef STAGE_A
#undef B_LOAD
#undef COMPUTE

    // epilogue: out[n,o] = acc * sx[n] * ws[o] + bias[o]
    // C/D: col = lane&31, row = (reg&3) + 8*(reg>>2) + 4*(lane>>5)  [m74/m101]
    #pragma unroll
    for (int j = 0; j < 2; ++j) {
        const int col = bn * BM + wn + j * 32 + l31;
        const float ws = wscale[col];
        const float bs = bias[col];
        #pragma unroll
        for (int i = 0; i < 4; ++i) {
            const int rb = bm * BM + wm + i * 32 + 4 * lh;
            #pragma unroll
            for (int r = 0; r < 16; ++r) {
                const int row = rb + (r & 3) + 8 * (r >> 2);
                out[(size_t)row * DIM + col] =
                    ((float)acc[i][j][r] * rowScale[row]) * ws + bs;
            }
        }
    }
}

// ---------------------------------------------------------------------------
extern "C" void kernel_launch(void* const* d_in, const int* in_sizes, int n_in,
                              void* d_out, int out_size, void* d_ws, size_t ws_size,
                              hipStream_t stream) {
    const float* x      = (const float*)d_in[0];
    const int*   wint   = (const int*)d_in[1];
    const float* wscale = (const float*)d_in[2];
    const float* bias   = (const float*)d_in[3];
    float* out = (float*)d_out;

    signed char* q8 = (signed char*)d_ws;                         // 16 MB
    signed char* w8 = q8 + (size_t)DIM * DIM;                     // 16 MB
    float* sx = (float*)(w8 + (size_t)DIM * DIM);                 // 16 KB

    prep<<<4096 + 16384, 256, 0, stream>>>(x, wint, q8, w8, sx);
    gemm_q8<<<dim3(DIM / BM, DIM / BM), 512, 0, stream>>>(q8, w8, sx, wscale, bias, out);
}

// Round 16
// 242.121 us; speedup vs baseline: 1.1733x; 1.1733x over previous
//
#include <hip/hip_runtime.h>
#include <math.h>

typedef int v4i  __attribute__((ext_vector_type(4)));
typedef int v16i __attribute__((ext_vector_type(16)));

#define DIM 4096
#define BM 256              // output tile (BM x BM)
#define BK 64               // K-tile bytes (int8)
#define ATILE (BM * BK)     // 16384 B per operand tile
#define BUFSZ (2 * ATILE)   // 32768 B per buffer (A | B)

// ---------------------------------------------------------------------------
// async global->LDS 16B copy (wave-uniform base + lane*16 destination rule)
// ---------------------------------------------------------------------------
__device__ __forceinline__ void async16(const void* g, void* l) {
    __builtin_amdgcn_global_load_lds((__attribute__((address_space(1))) void*)(g),
                                     (__attribute__((address_space(3))) void*)(l),
                                     16, 0, 0);
}

// raw barrier / counted waitcnt (T4): no implicit vmcnt(0) drain.
#define VMCNT(N) asm volatile("s_waitcnt vmcnt(" #N ")" ::: "memory")
#define BARRIER() asm volatile("s_barrier" ::: "memory")

// Bank swizzle over the 4 16B chunks of a 64B row (R10, best-measured).
__device__ __forceinline__ int swzC(int r) {
    return ((r >> 1) & 3) ^ ((r >> 3) & 3);
}

// ---------------------------------------------------------------------------
// Fused prep (passed R10/R11/R13/R14/R15): FWHT(256)+quant via rinv multiply;
// weight narrowing int32->int8.
// ---------------------------------------------------------------------------
__global__ __launch_bounds__(256) void prep(const float* __restrict__ x,
                                            const int* __restrict__ w,
                                            signed char* __restrict__ q,
                                            signed char* __restrict__ w8,
                                            float* __restrict__ scales) {
    if (blockIdx.x >= 4096) {
        int i = (blockIdx.x - 4096) * 256 + threadIdx.x;
        int4 v = ((const int4*)w)[i];
        char4 c;
        c.x = (signed char)v.x; c.y = (signed char)v.y;
        c.z = (signed char)v.z; c.w = (signed char)v.w;
        ((char4*)w8)[i] = c;
        return;
    }
    const int row  = blockIdx.x;
    const int lane = threadIdx.x & 63;
    const int wave = threadIdx.x >> 6;
    const float4* xr4 = (const float4*)(x + (size_t)row * DIM);

    float sgn[6];
    #pragma unroll
    for (int i = 0; i < 6; ++i) sgn[i] = (lane & (1 << i)) ? -1.0f : 1.0f;

    float f[4][4];                      // UNSCALED FWHT values (x 16 vs ref)
    #pragma unroll
    for (int b = 0; b < 4; ++b) {
        const int blk = wave + 4 * b;
        float4 v = xr4[blk * 64 + lane];
        float t0 = v.x + v.y, t1 = v.x - v.y;
        float t2 = v.z + v.w, t3 = v.z - v.w;
        f[b][0] = t0 + t2; f[b][1] = t1 + t3;
        f[b][2] = t0 - t2; f[b][3] = t1 - t3;
        #pragma unroll
        for (int st = 0; st < 6; ++st) {
            const int m = 1 << st;
            #pragma unroll
            for (int j = 0; j < 4; ++j) {
                float p = __shfl_xor(f[b][j], m, 64);
                f[b][j] = fmaf(sgn[st], f[b][j], p);
            }
        }
    }

    float m = 0.0f;
    #pragma unroll
    for (int b = 0; b < 4; ++b)
        #pragma unroll
        for (int j = 0; j < 4; ++j) m = fmaxf(m, fabsf(f[b][j]));
    #pragma unroll
    for (int d = 32; d; d >>= 1) m = fmaxf(m, __shfl_xor(m, d, 64));
    __shared__ float sm[4];
    if (lane == 0) sm[wave] = m;
    __syncthreads();
    m = fmaxf(fmaxf(sm[0], sm[1]), fmaxf(sm[2], sm[3]));

    const float s = (m * 0.0625f) / 7.0f;   // identical value to verified ver.
    if (threadIdx.x == 0) scales[row] = s;
    const float rinv = 7.0f / m;            // quant reciprocal (unscaled dom.)

    char4* qr4 = (char4*)(q + (size_t)row * DIM);
    #pragma unroll
    for (int b = 0; b < 4; ++b) {
        const int blk = wave + 4 * b;
        char4 c;
        int qi;
        qi = (int)rintf(f[b][0] * rinv); c.x = (signed char)min(7, max(-8, qi));
        qi = (int)rintf(f[b][1] * rinv); c.y = (signed char)min(7, max(-8, qi));
        qi = (int)rintf(f[b][2] * rinv); c.z = (signed char)min(7, max(-8, qi));
        qi = (int)rintf(f[b][3] * rinv); c.w = (signed char)min(7, max(-8, qi));
        qr4[blk * 64 + lane] = c;
    }
}

// ---------------------------------------------------------------------------
// int8 GEMM, 256x256 tile, BK=64, 8 waves (2M x 4N), quad-buffered LDS.
//
// Model (R10-R15): LDS port (~1400 cyc/tile/CU) and MFMA (~1170) run
// SERIALLY when MFMAs consume just-issued reads -> 3251 cyc/tile, util 33%.
// R16 = tile-level fragment pipeline on the R10 skeleton:
//   MFMA(t) consumes frags read in substep t-1 (zero lgkm wait at substep
//   top -> matrix pipe starts immediately); the port concurrently serves
//   RD_S1(t) + RD_S0(t+1) under the MFMA clusters.
// R14 tried this but its fragment-order DMA source was row-scattered
// (uncoalesced, the real regression cause -- also killed R15's direct-B).
// Here staging is R10's coalesced pattern (4 consecutive threads = 64B of
// one row), LDS dest linear, read offsets swizzled (4/read const cost,
// proven irrelevant by R14's conflicts->0 null result).
// Hazards: VMCNT(4)+barrier at substep t proves tile t+1 landed before
// RD_S0(t+1); STAGE(t+3) writes buf (t-1)&3 whose last ds_read was in
// substep t-2.  Frag regs: 12 v4i (48) with same-substep WAR reuse
// (R14-verified VGPR=128, 2 waves/SIMD preserved).
// ---------------------------------------------------------------------------
__global__ __launch_bounds__(512, 2) void gemm_q8(const signed char* __restrict__ A,
                                                  const signed char* __restrict__ B,
                                                  const float* __restrict__ rowScale,
                                                  const float* __restrict__ wscale,
                                                  const float* __restrict__ bias,
                                                  float* __restrict__ out) {
    __shared__ __align__(16) signed char S[4 * BUFSZ];   // 128 KB

    // XCD swizzle: 256 blocks -> each XCD a 4(bm) x 8(bn) rectangle.
    const int flat = blockIdx.y * gridDim.x + blockIdx.x;
    const int xcd  = flat & 7;
    const int idx  = flat >> 3;                 // 0..31
    const int bm   = ((xcd >> 1) << 2) + (idx & 3);
    const int bn   = ((xcd & 1) << 3) + (idx >> 2);

    const int t = threadIdx.x;
    const int lane = t & 63;
    const int wave = t >> 6;                    // 0..7
    const int wm = (wave >> 2) * 128;           // 2 waves in M
    const int wn = (wave & 3) * 64;             // 4 waves in N
    const int l31 = lane & 31, lh = lane >> 5;

    // --- staging: R10 coalesced pattern. thread t covers dest chunks
    // cidx = t and t+512; row = cidx>>2, chunk = (cidx&3)^swzC(row).
    const signed char* ga[2];
    const signed char* gb[2];
    int ldsA[2], ldsB[2];
    #pragma unroll
    for (int h = 0; h < 2; ++h) {
        const int cidx = t + 512 * h;           // 0..1023
        const int row  = cidx >> 2;             // 0..255
        const int g    = (cidx & 3) ^ swzC(row);// pre-swizzled global chunk
        ga[h] = A + (size_t)(bm * BM + row) * DIM + g * 16;
        gb[h] = B + (size_t)(bn * BM + row) * DIM + g * 16;
        ldsA[h] = cidx * 16;                    // linear LDS dest (A region)
        ldsB[h] = ATILE + cidx * 16;            // linear LDS dest (B region)
    }

    // --- loop-invariant read offsets (within one buffer)
    int offA[4][2], offB[2][2];
    #pragma unroll
    for (int i = 0; i < 4; ++i)
        #pragma unroll
        for (int s = 0; s < 2; ++s) {
            const int r = wm + i * 32 + l31;
            offA[i][s] = r * BK + (((2 * s + lh) ^ swzC(r)) * 16);
        }
    #pragma unroll
    for (int j = 0; j < 2; ++j)
        #pragma unroll
        for (int s = 0; s < 2; ++s) {
            const int c = wn + j * 32 + l31;
            offB[j][s] = ATILE + c * BK + (((2 * s + lh) ^ swzC(c)) * 16);
        }

    v16i acc[4][2] = {};
    v4i fa0[4], fb0[2];                 // s=0 fragment set (pipelined)
    v4i fa1[4], fb1[2];                 // s=1 fragment set

#define STAGE(P) do {                                                          \
        async16(ga[0], &S[(P) * BUFSZ + ldsA[0]]); ga[0] += BK;                \
        async16(ga[1], &S[(P) * BUFSZ + ldsA[1]]); ga[1] += BK;                \
        async16(gb[0], &S[(P) * BUFSZ + ldsB[0]]); gb[0] += BK;                \
        async16(gb[1], &S[(P) * BUFSZ + ldsB[1]]); gb[1] += BK;                \
    } while (0)

#define RD_S0(P) do {                                                          \
        fa0[0] = *(const v4i*)&S[(P) * BUFSZ + offA[0][0]];                    \
        fa0[1] = *(const v4i*)&S[(P) * BUFSZ + offA[1][0]];                    \
        fa0[2] = *(const v4i*)&S[(P) * BUFSZ + offA[2][0]];                    \
        fa0[3] = *(const v4i*)&S[(P) * BUFSZ + offA[3][0]];                    \
        fb0[0] = *(const v4i*)&S[(P) * BUFSZ + offB[0][0]];                    \
        fb0[1] = *(const v4i*)&S[(P) * BUFSZ + offB[1][0]];                    \
    } while (0)

#define RD_S1(P) do {                                                          \
        fa1[0] = *(const v4i*)&S[(P) * BUFSZ + offA[0][1]];                    \
        fa1[1] = *(const v4i*)&S[(P) * BUFSZ + offA[1][1]];                    \
        fa1[2] = *(const v4i*)&S[(P) * BUFSZ + offA[2][1]];                    \
        fa1[3] = *(const v4i*)&S[(P) * BUFSZ + offA[3][1]];                    \
        fb1[0] = *(const v4i*)&S[(P) * BUFSZ + offB[0][1]];                    \
        fb1[1] = *(const v4i*)&S[(P) * BUFSZ + offB[1][1]];                    \
    } while (0)

#define MFMA8(FA, FB) do {                                                     \
        __builtin_amdgcn_s_setprio(1);                                         \
        acc[0][0] = __builtin_amdgcn_mfma_i32_32x32x32_i8(FA[0], FB[0], acc[0][0], 0, 0, 0); \
        acc[0][1] = __builtin_amdgcn_mfma_i32_32x32x32_i8(FA[0], FB[1], acc[0][1], 0, 0, 0); \
        acc[1][0] = __builtin_amdgcn_mfma_i32_32x32x32_i8(FA[1], FB[0], acc[1][0], 0, 0, 0); \
        acc[1][1] = __builtin_amdgcn_mfma_i32_32x32x32_i8(FA[1], FB[1], acc[1][1], 0, 0, 0); \
        acc[2][0] = __builtin_amdgcn_mfma_i32_32x32x32_i8(FA[2], FB[0], acc[2][0], 0, 0, 0); \
        acc[2][1] = __builtin_amdgcn_mfma_i32_32x32x32_i8(FA[2], FB[1], acc[2][1], 0, 0, 0); \
        acc[3][0] = __builtin_amdgcn_mfma_i32_32x32x32_i8(FA[3], FB[0], acc[3][0], 0, 0, 0); \
        acc[3][1] = __builtin_amdgcn_mfma_i32_32x32x32_i8(FA[3], FB[1], acc[3][1], 0, 0, 0); \
        __builtin_amdgcn_s_setprio(0);                                         \
    } while (0)

    // Substep t: compute tile P=t&3 (s0 frags preloaded last substep),
    // read s1(t) + s0(t+1) under the MFMA clusters, stage tile t+3.
#define SUBSTEP(P, PN, SP, VN) do {                                            \
        VMCNT(VN); BARRIER();        /* tiles..t+1 landed; buf SP free */      \
        STAGE(SP);                                                             \
        RD_S1(P);                    /* port works under s0 MFMAs */           \
        MFMA8(fa0, fb0);             /* s0 of tile t: zero lgkm wait */        \
        RD_S0(PN);                   /* s0 of tile t+1 (landed) */             \
        MFMA8(fa1, fb1);             /* s1 of tile t */                        \
    } while (0)

#define SUBSTEP_NS(P, PN, VN) do {                                             \
        VMCNT(VN); BARRIER();                                                  \
        RD_S1(P);                                                              \
        MFMA8(fa0, fb0);                                                       \
        RD_S0(PN);                                                             \
        MFMA8(fa1, fb1);                                                       \
    } while (0)

    // 64 K-tiles, tile t -> buf t&3.  Prologue stages 0,1,2; preloads s0(0).
    STAGE(0); STAGE(1); STAGE(2);
    VMCNT(8); BARRIER();             // tile 0 landed everywhere
    RD_S0(0);
    #pragma unroll 1
    for (int it = 0; it < 15; ++it) {          // substeps 0..59
        SUBSTEP(0, 1, 3, 4);         // compute 4it+0, stage 4it+3
        SUBSTEP(1, 2, 0, 4);         // compute 4it+1, stage 4it+4
        SUBSTEP(2, 3, 1, 4);         // compute 4it+2, stage 4it+5
        SUBSTEP(3, 0, 2, 4);         // compute 4it+3, stage 4it+6
    }
    SUBSTEP(0, 1, 3, 4);             // substep 60: compute 60, stage 63
    SUBSTEP_NS(1, 2, 4);             // substep 61: compute 61, read s0(62)
    SUBSTEP_NS(2, 3, 0);             // substep 62: compute 62, read s0(63)
    RD_S1(3);                        // substep 63: compute 63
    MFMA8(fa0, fb0);
    MFMA8(fa1, fb1);

#undef SUBSTEP
#undef SUBSTEP_NS
#undef STAGE
#undef RD_S0
#undef RD_S1
#undef MFMA8

    // epilogue: out[n,o] = acc * sx[n] * ws[o] + bias[o]
    // C/D: col = lane&31, row = (reg&3) + 8*(reg>>2) + 4*(lane>>5)  [m74/m101]
    #pragma unroll
    for (int j = 0; j < 2; ++j) {
        const int col = bn * BM + wn + j * 32 + l31;
        const float ws = wscale[col];
        const float bs = bias[col];
        #pragma unroll
        for (int i = 0; i < 4; ++i) {
            const int rb = bm * BM + wm + i * 32 + 4 * lh;
            #pragma unroll
            for (int r = 0; r < 16; ++r) {
                const int row = rb + (r & 3) + 8 * (r >> 2);
                out[(size_t)row * DIM + col] =
                    ((float)acc[i][j][r] * rowScale[row]) * ws + bs;
            }
        }
    }
}

// ---------------------------------------------------------------------------
extern "C" void kernel_launch(void* const* d_in, const int* in_sizes, int n_in,
                              void* d_out, int out_size, void* d_ws, size_t ws_size,
                              hipStream_t stream) {
    const float* x      = (const float*)d_in[0];
    const int*   wint   = (const int*)d_in[1];
    const float* wscale = (const float*)d_in[2];
    const float* bias   = (const float*)d_in[3];
    float* out = (float*)d_out;

    signed char* q8 = (signed char*)d_ws;                         // 16 MB
    signed char* w8 = q8 + (size_t)DIM * DIM;                     // 16 MB
    float* sx = (float*)(w8 + (size_t)DIM * DIM);                 // 16 KB

    prep<<<4096 + 16384, 256, 0, stream>>>(x, wint, q8, w8, sx);
    gemm_q8<<<dim3(DIM / BM, DIM / BM), 512, 0, stream>>>(q8, w8, sx, wscale, bias, out);
}